// Round 9
// baseline (331.823 us; speedup 1.0000x reference)
//
#include <hip/hip_runtime.h>
#include <hip/hip_bf16.h>
#include <stdint.h>

#define BATCH 4
#define SEQ   4096          // 64*64 spatial
#define CH    512
#define NGRP  32
#define GEPS  1e-6f

typedef short  short8  __attribute__((ext_vector_type(8)));
typedef float  floatx4 __attribute__((ext_vector_type(4)));

static __device__ __forceinline__ short bf16b(float f) {
    __hip_bfloat16 h = __float2bfloat16(f);
    return __builtin_bit_cast(short, h);
}
static __device__ __forceinline__ float bf2f(short s) {
    unsigned u = ((unsigned)(unsigned short)s) << 16;
    return __builtin_bit_cast(float, u);
}
static __device__ __forceinline__ char fp8b(float f) {
    int pk = __builtin_amdgcn_cvt_pk_fp8_f32(f, f, 0, false);
    return (char)(pk & 0xff);
}

// async global->LDS, 16B per lane. LDS dest = wave-uniform base + lane*16.
static __device__ __forceinline__ void dma16(const void* g, void* l) {
    __builtin_amdgcn_global_load_lds(
        (const __attribute__((address_space(1))) unsigned int*)g,
        (__attribute__((address_space(3))) unsigned int*)l, 16, 0, 0);
}

// max-reduce across the 16 lanes of a DPP row, pure VALU
static __device__ __forceinline__ float rowmax16(float x) {
    int xi = __builtin_bit_cast(int, x);
    x = fmaxf(x, __builtin_bit_cast(float, __builtin_amdgcn_update_dpp(xi, xi, 0x128, 0xf, 0xf, true))); // row_ror:8
    xi = __builtin_bit_cast(int, x);
    x = fmaxf(x, __builtin_bit_cast(float, __builtin_amdgcn_update_dpp(xi, xi, 0x124, 0xf, 0xf, true))); // row_ror:4
    xi = __builtin_bit_cast(int, x);
    x = fmaxf(x, __builtin_bit_cast(float, __builtin_amdgcn_update_dpp(xi, xi, 0x122, 0xf, 0xf, true))); // row_ror:2
    xi = __builtin_bit_cast(int, x);
    x = fmaxf(x, __builtin_bit_cast(float, __builtin_amdgcn_update_dpp(xi, xi, 0x121, 0xf, 0xf, true))); // row_ror:1
    return x;
}

// ---------------- GroupNorm partial sums ----------------
__global__ __launch_bounds__(256) void gn_partial_kernel(const float* __restrict__ x,
                                                         float* __restrict__ statsraw) {
    int blk = blockIdx.x;                 // 0..255
    int t = threadIdx.x;
    size_t row0 = (size_t)blk * 64;
    int qd = t & 127;
    int rh = t >> 7;
    const float* base = x + row0 * 512 + qd * 4;
    float s1 = 0.f, s2 = 0.f;
    #pragma unroll 4
    for (int i = 0; i < 32; ++i) {
        int r = rh + i * 2;
        float4 v = *reinterpret_cast<const float4*>(base + (size_t)r * 512);
        s1 += v.x + v.y + v.z + v.w;
        s2 += v.x * v.x + v.y * v.y + v.z * v.z + v.w * v.w;
    }
    __shared__ float a1[256], a2[256];
    a1[t] = s1; a2[t] = s2;
    __syncthreads();
    if (t < 32) {
        float u1 = 0.f, u2 = 0.f;
        #pragma unroll
        for (int e = 0; e < 4; ++e) {
            u1 += a1[t * 4 + e] + a1[128 + t * 4 + e];
            u2 += a2[t * 4 + e] + a2[128 + t * 4 + e];
        }
        int b = (int)(row0 >> 12);
        atomicAdd(&statsraw[(b * 32 + t) * 2],     u1);
        atomicAdd(&statsraw[(b * 32 + t) * 2 + 1], u2);
    }
}

// ---------------- GroupNorm apply ----------------
__global__ __launch_bounds__(256) void gn_apply_kernel(const float* __restrict__ x,
                                                       const float* __restrict__ statsraw,
                                                       const float* __restrict__ gsc,
                                                       const float* __restrict__ gbs,
                                                       short* __restrict__ xn) {
    int i4 = blockIdx.x * 256 + threadIdx.x;
    int base = i4 * 4;
    int b = base >> 21;
    int c = base & 511;
    int sidx = (b * 32 + (c >> 4)) * 2;
    float s1 = statsraw[sidx], s2 = statsraw[sidx + 1];
    float mean = s1 * (1.f / 65536.f);
    float var  = s2 * (1.f / 65536.f) - mean * mean;
    float rstd = rsqrtf(var + GEPS);
    float4 xv = reinterpret_cast<const float4*>(x)[i4];
    float4 sv = *reinterpret_cast<const float4*>(gsc + c);
    float4 bv = *reinterpret_cast<const float4*>(gbs + c);
    union { short s[4]; uint2 u; } p;
    p.s[0] = bf16b((xv.x - mean) * rstd * sv.x + bv.x);
    p.s[1] = bf16b((xv.y - mean) * rstd * sv.y + bv.y);
    p.s[2] = bf16b((xv.z - mean) * rstd * sv.z + bv.z);
    p.s[3] = bf16b((xv.w - mean) * rstd * sv.w + bv.w);
    reinterpret_cast<uint2*>(xn)[i4] = p.u;
}

// ---------------- weight transpose ----------------
__global__ __launch_bounds__(256) void wtrans_kernel(const float* __restrict__ w0,
                                                     const float* __restrict__ w1,
                                                     const float* __restrict__ w2,
                                                     const float* __restrict__ w3,
                                                     short* __restrict__ wT) {
    const float* w = (blockIdx.z == 0) ? w0 : (blockIdx.z == 1) ? w1
                   : (blockIdx.z == 2) ? w2 : w3;
    short* out = wT + (size_t)blockIdx.z * CH * CH;
    int n0 = blockIdx.x * 32, k0 = blockIdx.y * 32;
    int tx = threadIdx.x, ty = threadIdx.y;
    __shared__ float s[32][33];
    #pragma unroll
    for (int i = 0; i < 4; ++i) {
        int kk = ty + i * 8;
        s[kk][tx] = w[(size_t)(k0 + kk) * CH + n0 + tx];
    }
    __syncthreads();
    #pragma unroll
    for (int i = 0; i < 4; ++i) {
        int nn = ty + i * 8;
        out[(size_t)(n0 + nn) * CH + k0 + tx] = bf16b(s[tx][nn]);
    }
}

// ---------------- fused QKV GEMM: fp8 epilogue (q8/k8 row-major, v via LDS transpose) ----
__global__ __launch_bounds__(256) void gemm_qkv_kernel(const short* __restrict__ A,
                                                       const short* __restrict__ wT,
                                                       const float* __restrict__ bq,
                                                       const float* __restrict__ bk,
                                                       const float* __restrict__ bv,
                                                       char* __restrict__ q8,
                                                       char* __restrict__ k8,
                                                       char* __restrict__ vT8) {
    __shared__ short As[128 * 64];
    __shared__ short Bs[128 * 64];
    __shared__ char  vls[128 * 144];   // fp8 transpose staging, pitch 144 (16B-aligned, banked)
    int m0 = blockIdx.x * 128;
    int nblk = blockIdx.y;                  // 0..11
    int which = nblk >> 2;                  // 0=q,1=k,2=v (block-uniform)
    int n0 = (nblk & 3) * 128;
    const short* BT = wT + (size_t)which * 512 * 512;
    const float* bias = (which == 0) ? bq : (which == 1) ? bk : bv;
    int t = threadIdx.x;
    int w = t >> 6, lane = t & 63;
    int wr = w >> 1, wc = w & 1;
    int l15 = lane & 15, l4 = lane >> 4;
    floatx4 acc[4][4];
    #pragma unroll
    for (int i = 0; i < 4; ++i)
        #pragma unroll
        for (int j = 0; j < 4; ++j) acc[i][j] = (floatx4){0.f, 0.f, 0.f, 0.f};

    for (int k0 = 0; k0 < 512; k0 += 64) {
        __syncthreads();
        #pragma unroll
        for (int i = 0; i < 4; ++i) {
            int c = i * 256 + t;
            int row = c >> 3, j = (c & 7) ^ (row & 7);
            dma16(&A[(size_t)(m0 + row) * 512 + k0 + j * 8], &As[(c & ~63) * 8]);
            dma16(&BT[(size_t)(n0 + row) * 512 + k0 + j * 8], &Bs[(c & ~63) * 8]);
        }
        __syncthreads();
        #pragma unroll
        for (int kk = 0; kk < 64; kk += 32) {
            short8 af[4], bf[4];
            #pragma unroll
            for (int i = 0; i < 4; ++i) {
                int row = wr * 64 + i * 16 + l15;
                int j = (kk >> 3) + l4;
                af[i] = *reinterpret_cast<const short8*>(&As[(row * 8 + (j ^ (l15 & 7))) * 8]);
            }
            #pragma unroll
            for (int j2 = 0; j2 < 4; ++j2) {
                int row = wc * 64 + j2 * 16 + l15;
                int j = (kk >> 3) + l4;
                bf[j2] = *reinterpret_cast<const short8*>(&Bs[(row * 8 + (j ^ (l15 & 7))) * 8]);
            }
            #pragma unroll
            for (int i = 0; i < 4; ++i)
                #pragma unroll
                for (int j2 = 0; j2 < 4; ++j2)
                    acc[i][j2] = __builtin_amdgcn_mfma_f32_16x16x32_bf16(af[i], bf[j2], acc[i][j2], 0, 0, 0);
        }
    }
    if (which < 2) {
        char* o8 = (which == 0) ? q8 : k8;
        #pragma unroll
        for (int i = 0; i < 4; ++i)
            #pragma unroll
            for (int j = 0; j < 4; ++j)
                #pragma unroll
                for (int r = 0; r < 4; ++r) {
                    int row = m0 + wr * 64 + i * 16 + l4 * 4 + r;
                    int col = n0 + wc * 64 + j * 16 + l15;
                    o8[(size_t)row * 512 + col] = fp8b(acc[i][j][r] + bias[col]);
                }
    } else {
        // stage fp8 transpose through LDS, then coalesced 16B stores
        __syncthreads();
        #pragma unroll
        for (int i = 0; i < 4; ++i)
            #pragma unroll
            for (int j = 0; j < 4; ++j)
                #pragma unroll
                for (int r = 0; r < 4; ++r) {
                    int rl = wr * 64 + i * 16 + l4 * 4 + r;     // local row (l)
                    int cl = wc * 64 + j * 16 + l15;            // local col (d)
                    vls[cl * 144 + rl] = fp8b(acc[i][j][r] + bias[n0 + cl]);
                }
        __syncthreads();
        int b = m0 >> 12, l0 = m0 & 4095;
        #pragma unroll
        for (int p = 0; p < 4; ++p) {
            int slot = p * 256 + t;
            int c = slot >> 3, off = (slot & 7) * 16;
            uint4 v = *reinterpret_cast<const uint4*>(&vls[c * 144 + off]);
            *reinterpret_cast<uint4*>(&vT8[((size_t)b * 512 + n0 + c) * 4096 + l0 + off]) = v;
        }
    }
}

// ---------------- output GEMM: bias + residual, fp32 out ----------------
__global__ __launch_bounds__(256) void gemm_bt_kernel(const short* __restrict__ A,
                                                      const short* __restrict__ BT,
                                                      const float* __restrict__ bias,
                                                      float* __restrict__ outf,
                                                      const float* __restrict__ resid) {
    __shared__ short As[128 * 64];
    __shared__ short Bs[128 * 64];
    int m0 = blockIdx.x * 128, n0 = blockIdx.y * 128;
    int t = threadIdx.x;
    int w = t >> 6, lane = t & 63;
    int wr = w >> 1, wc = w & 1;
    int l15 = lane & 15, l4 = lane >> 4;
    floatx4 acc[4][4];
    #pragma unroll
    for (int i = 0; i < 4; ++i)
        #pragma unroll
        for (int j = 0; j < 4; ++j) acc[i][j] = (floatx4){0.f, 0.f, 0.f, 0.f};

    for (int k0 = 0; k0 < 512; k0 += 64) {
        __syncthreads();
        #pragma unroll
        for (int i = 0; i < 4; ++i) {
            int c = i * 256 + t;
            int row = c >> 3, j = (c & 7) ^ (row & 7);
            dma16(&A[(size_t)(m0 + row) * 512 + k0 + j * 8], &As[(c & ~63) * 8]);
            dma16(&BT[(size_t)(n0 + row) * 512 + k0 + j * 8], &Bs[(c & ~63) * 8]);
        }
        __syncthreads();
        #pragma unroll
        for (int kk = 0; kk < 64; kk += 32) {
            short8 af[4], bf[4];
            #pragma unroll
            for (int i = 0; i < 4; ++i) {
                int row = wr * 64 + i * 16 + l15;
                int j = (kk >> 3) + l4;
                af[i] = *reinterpret_cast<const short8*>(&As[(row * 8 + (j ^ (l15 & 7))) * 8]);
            }
            #pragma unroll
            for (int j2 = 0; j2 < 4; ++j2) {
                int row = wc * 64 + j2 * 16 + l15;
                int j = (kk >> 3) + l4;
                bf[j2] = *reinterpret_cast<const short8*>(&Bs[(row * 8 + (j ^ (l15 & 7))) * 8]);
            }
            #pragma unroll
            for (int i = 0; i < 4; ++i)
                #pragma unroll
                for (int j2 = 0; j2 < 4; ++j2)
                    acc[i][j2] = __builtin_amdgcn_mfma_f32_16x16x32_bf16(af[i], bf[j2], acc[i][j2], 0, 0, 0);
        }
    }
    #pragma unroll
    for (int i = 0; i < 4; ++i)
        #pragma unroll
        for (int j = 0; j < 4; ++j)
            #pragma unroll
            for (int r = 0; r < 4; ++r) {
                int row = m0 + wr * 64 + i * 16 + l4 * 4 + r;
                int col = n0 + wc * 64 + j * 16 + l15;
                float vv = acc[i][j][r] + bias[col];
                outf[(size_t)row * 512 + col] = vv + resid[(size_t)row * 512 + col];
            }
}

// ---------------- flash attention: fp8, pipelined dbuf, XCD-local (part,b) ---------
// Flat 512-block grid. pb = bx & 7 -> all blocks on one XCD share one (part,b), so the
// XCD's 4MB L2 holds that (part,b)'s K+V halves (2MB) -> staging becomes L2 hits.
__global__ __launch_bounds__(256, 2) void flash_kernel(const char* __restrict__ q8,
                                                       const char* __restrict__ k8,
                                                       const char* __restrict__ v8,
                                                       short* __restrict__ Opart,
                                                       float* __restrict__ ml) {
    __shared__ __align__(16) char smem[68096];
    int bx = blockIdx.x;                 // 0..511
    int pb = bx & 7;
    int part = pb >> 2, b = pb & 3;
    int q0 = (bx >> 3) * 64;
    int t = threadIdx.x, w = t >> 6, lane = t & 63;
    int l15 = lane & 15, l4 = lane >> 4;
    const float scale = 0.044194173824159216f;  // 1/sqrt(512)

    // Q fp8 fragments: rows w*16 + l15, all 512 k (8 B per ks-step)
    long qf[16];
    {
        const char* qrow = q8 + ((size_t)b * SEQ + q0 + w * 16 + l15) * 512;
        #pragma unroll
        for (int ks = 0; ks < 16; ++ks)
            qf[ks] = *reinterpret_cast<const long*>(qrow + ks * 32 + l4 * 8);
    }

    floatx4 acc[32];
    #pragma unroll
    for (int i = 0; i < 32; ++i) acc[i] = (floatx4){0.f, 0.f, 0.f, 0.f};
    floatx4 lacc = (floatx4){0.f, 0.f, 0.f, 0.f};
    float mused[4] = {-1e30f, -1e30f, -1e30f, -1e30f};

    const long ones = 0x3838383838383838L;   // e4m3 1.0 x8

    const char* kbase = k8 + (size_t)b * SEQ * 512;
    const char* vbase = v8 + (size_t)b * 512 * SEQ;

    const int kswz = l15 & 7;
    const int vswz = (l4 >> 1) ^ ((l15 >> 2) & 1);
    const int koff = (l4 & 1) * 8;
    const int s_begin = part * (SEQ / 2);

    // stage: K tile 32x512B, V tile 512x32B; 256 thr -> 4+4 dma16
    auto stage = [&](int s0, int buf) {
        char* Kd = smem + buf * 16384;
        char* Vd = smem + 32768 + buf * 16384;
        #pragma unroll
        for (int i = 0; i < 4; ++i) {
            int c = i * 256 + t;
            int row = c >> 5, j = (c & 31) ^ (row & 7);
            dma16(kbase + (size_t)(s0 + row) * 512 + j * 16, Kd + (size_t)(c & ~63) * 16);
        }
        #pragma unroll
        for (int i = 0; i < 4; ++i) {
            int c = i * 256 + t;
            int d = c >> 1, j = (c & 1) ^ ((d >> 2) & 1);
            dma16(vbase + (size_t)d * SEQ + s0 + j * 16, Vd + (size_t)(c & ~63) * 16);
        }
    };

    stage(s_begin, 0);
    __syncthreads();                                   // tile 0 ready

    for (int it = 0; it < 64; ++it) {
        int cur = it & 1;
        if (it + 1 < 64) stage(s_begin + (it + 1) * 32, 1 - cur);

        const char* Kb = smem + cur * 16384;
        const char* Vb = smem + 32768 + cur * 16384;

        // --- QK^T (fp8): S[16 rows][32 cols] in two 16x16 C-tiles
        floatx4 sa0 = (floatx4){0.f, 0.f, 0.f, 0.f};
        floatx4 sa1 = (floatx4){0.f, 0.f, 0.f, 0.f};
        #pragma unroll
        for (int ks = 0; ks < 16; ++ks) {
            int jc = ks * 2 + (l4 >> 1);
            int a0 = (l15 * 32 + (jc ^ kswz)) * 16 + koff;
            long b0 = *reinterpret_cast<const long*>(Kb + a0);
            long b1 = *reinterpret_cast<const long*>(Kb + a0 + 8192);
            sa0 = __builtin_amdgcn_mfma_f32_16x16x32_fp8_fp8(qf[ks], b0, sa0, 0, 0, 0);
            sa1 = __builtin_amdgcn_mfma_f32_16x16x32_fp8_fp8(qf[ks], b1, sa1, 0, 0, 0);
        }

        // --- online softmax with lazy rescale (margin 5)
        float v0[4], v1[4], nm4[4];
        bool need = false;
        #pragma unroll
        for (int r = 0; r < 4; ++r) {
            v0[r] = sa0[r] * scale; v1[r] = sa1[r] * scale;
            nm4[r] = rowmax16(fmaxf(v0[r], v1[r]));
            need |= (nm4[r] > mused[r] + 5.0f);
        }
        if (__ballot(need)) {
            #pragma unroll
            for (int r = 0; r < 4; ++r) {
                float nm = fmaxf(mused[r], nm4[r]);
                float al = __expf(mused[r] - nm);
                lacc[r] *= al;
                #pragma unroll
                for (int i = 0; i < 32; ++i) acc[i][r] *= al;
                mused[r] = nm;
            }
        }
        float p0[4], p1[4];
        #pragma unroll
        for (int r = 0; r < 4; ++r) {
            p0[r] = __expf(v0[r] - mused[r]);     // <= e^5 = 148 < 448 fp8 max
            p1[r] = __expf(v1[r] - mused[r]);
        }

        // P (fp8) write to wave-private region (pitch 40 B)
        char* Ps = smem + 65536 + w * 640;
        #pragma unroll
        for (int r = 0; r < 4; ++r) {
            int pk = __builtin_amdgcn_cvt_pk_fp8_f32(p0[r], p1[r], 0, false);
            Ps[(l4 * 4 + r) * 40 + l15]      = (char)(pk & 0xff);
            Ps[(l4 * 4 + r) * 40 + 16 + l15] = (char)((pk >> 8) & 0xff);
        }

        long pf = *reinterpret_cast<const long*>(Ps + l15 * 40 + l4 * 8);
        lacc = __builtin_amdgcn_mfma_f32_16x16x32_fp8_fp8(pf, ones, lacc, 0, 0, 0);
        #pragma unroll
        for (int tt = 0; tt < 32; ++tt) {
            int d = tt * 16 + l15;
            long vf = *reinterpret_cast<const long*>(Vb + (d * 2 + vswz) * 16 + koff);
            acc[tt] = __builtin_amdgcn_mfma_f32_16x16x32_fp8_fp8(pf, vf, acc[tt], 0, 0, 0);
        }

        __syncthreads();    // drains DMA(i+1) + all reads of buf[cur] done
    }

    short* obase = Opart + (((size_t)part * BATCH + b) * SEQ + q0 + w * 16) * 512;
    #pragma unroll
    for (int r = 0; r < 4; ++r) {
        #pragma unroll
        for (int tt = 0; tt < 32; ++tt)
            obase[(size_t)(l4 * 4 + r) * 512 + tt * 16 + l15] = bf16b(acc[tt][r]);
    }
    if (l15 == 0) {
        #pragma unroll
        for (int r = 0; r < 4; ++r) {
            size_t rowg = ((size_t)part * BATCH + b) * SEQ + q0 + w * 16 + l4 * 4 + r;
            ml[rowg * 2]     = mused[r];
            ml[rowg * 2 + 1] = lacc[r];
        }
    }
}

// ---------------- combine ----------------
__global__ __launch_bounds__(256) void combine_kernel(const short* __restrict__ Opart,
                                                      const float* __restrict__ ml,
                                                      short* __restrict__ attn) {
    int i8 = blockIdx.x * 256 + threadIdx.x;
    size_t row = (size_t)i8 >> 6;
    float m0 = ml[row * 2], l0 = ml[row * 2 + 1];
    float m1 = ml[((size_t)BATCH * SEQ + row) * 2], l1 = ml[((size_t)BATCH * SEQ + row) * 2 + 1];
    float m = fmaxf(m0, m1);
    float e0 = __expf(m0 - m), e1 = __expf(m1 - m);
    float inv = 1.f / (e0 * l0 + e1 * l1);
    e0 *= inv; e1 *= inv;
    union { uint4 u; short s[8]; } a, bb, o;
    a.u  = reinterpret_cast<const uint4*>(Opart)[i8];
    bb.u = reinterpret_cast<const uint4*>(Opart)[(size_t)BATCH * SEQ * 512 / 8 + i8];
    #pragma unroll
    for (int e = 0; e < 8; ++e)
        o.s[e] = bf16b(bf2f(a.s[e]) * e0 + bf2f(bb.s[e]) * e1);
    reinterpret_cast<uint4*>(attn)[i8] = o.u;
}

extern "C" void kernel_launch(void* const* d_in, const int* in_sizes, int n_in,
                              void* d_out, int out_size, void* d_ws, size_t ws_size,
                              hipStream_t stream) {
    const float* x   = (const float*)d_in[0];
    const float* gsc = (const float*)d_in[1];
    const float* gbs = (const float*)d_in[2];
    const float* wq  = (const float*)d_in[3];
    const float* bq  = (const float*)d_in[4];
    const float* wk  = (const float*)d_in[5];
    const float* bk  = (const float*)d_in[6];
    const float* wv  = (const float*)d_in[7];
    const float* bv  = (const float*)d_in[8];
    const float* wo  = (const float*)d_in[9];
    const float* bo  = (const float*)d_in[10];
    float* out = (float*)d_out;

    char* ws = (char*)d_ws;
    const size_t MB = 1ull << 20;
    // [0,16)  xn bf16 (GEMM A input); attn bf16 overlays after QKV GEMM (xn dead)
    // [16,24) q8; [24,32) k8; [32,40) vT8  (fp8, written by gemm_qkv epilogue)
    // [40,72) Opart bf16; [72,74) wT; [74,..) stats + ml
    short* xn    = (short*)ws;
    char*  q8    = (char*)(ws + 16 * MB);
    char*  k8    = (char*)(ws + 24 * MB);
    char*  vT8   = (char*)(ws + 32 * MB);
    short* Opart = (short*)(ws + 40 * MB);
    short* wT    = (short*)(ws + 72 * MB);
    float* stats = (float*)(ws + 74 * MB);
    float* ml    = (float*)(ws + 74 * MB + 65536);
    short* attn  = xn;

    hipMemsetAsync(stats, 0, 256 * sizeof(float), stream);
    gn_partial_kernel<<<256, 256, 0, stream>>>(x, stats);
    gn_apply_kernel<<<8192, 256, 0, stream>>>(x, stats, gsc, gbs, xn);
    wtrans_kernel<<<dim3(16, 16, 4), dim3(32, 8), 0, stream>>>(wq, wk, wv, wo, wT);

    short* woT = wT + 786432;

    gemm_qkv_kernel<<<dim3(128, 12), 256, 0, stream>>>(xn, wT, bq, bk, bv, q8, k8, vT8);
    flash_kernel<<<512, 256, 0, stream>>>(q8, k8, vT8, Opart, ml);
    combine_kernel<<<4096, 256, 0, stream>>>(Opart, ml, attn);
    gemm_bt_kernel<<<dim3(128, 4), 256, 0, stream>>>(attn, woT, bo, out, x);
}

// Round 11
// 320.815 us; speedup vs baseline: 1.0343x; 1.0343x over previous
//
#include <hip/hip_runtime.h>
#include <hip/hip_bf16.h>
#include <stdint.h>

#define BATCH 4
#define SEQ   4096          // 64*64 spatial
#define CH    512
#define NGRP  32
#define GEPS  1e-6f

typedef short  short8  __attribute__((ext_vector_type(8)));
typedef float  floatx4 __attribute__((ext_vector_type(4)));

static __device__ __forceinline__ short bf16b(float f) {
    __hip_bfloat16 h = __float2bfloat16(f);
    return __builtin_bit_cast(short, h);
}
static __device__ __forceinline__ float bf2f(short s) {
    unsigned u = ((unsigned)(unsigned short)s) << 16;
    return __builtin_bit_cast(float, u);
}
static __device__ __forceinline__ char fp8b(float f) {
    int pk = __builtin_amdgcn_cvt_pk_fp8_f32(f, f, 0, false);
    return (char)(pk & 0xff);
}

// async global->LDS, 16B per lane. LDS dest = wave-uniform base + lane*16.
static __device__ __forceinline__ void dma16(const void* g, void* l) {
    __builtin_amdgcn_global_load_lds(
        (const __attribute__((address_space(1))) unsigned int*)g,
        (__attribute__((address_space(3))) unsigned int*)l, 16, 0, 0);
}

// max-reduce across the 16 lanes of a DPP row, pure VALU
static __device__ __forceinline__ float rowmax16(float x) {
    int xi = __builtin_bit_cast(int, x);
    x = fmaxf(x, __builtin_bit_cast(float, __builtin_amdgcn_update_dpp(xi, xi, 0x128, 0xf, 0xf, true))); // row_ror:8
    xi = __builtin_bit_cast(int, x);
    x = fmaxf(x, __builtin_bit_cast(float, __builtin_amdgcn_update_dpp(xi, xi, 0x124, 0xf, 0xf, true))); // row_ror:4
    xi = __builtin_bit_cast(int, x);
    x = fmaxf(x, __builtin_bit_cast(float, __builtin_amdgcn_update_dpp(xi, xi, 0x122, 0xf, 0xf, true))); // row_ror:2
    xi = __builtin_bit_cast(int, x);
    x = fmaxf(x, __builtin_bit_cast(float, __builtin_amdgcn_update_dpp(xi, xi, 0x121, 0xf, 0xf, true))); // row_ror:1
    return x;
}

// ---------------- GroupNorm partial sums ----------------
__global__ __launch_bounds__(256) void gn_partial_kernel(const float* __restrict__ x,
                                                         float* __restrict__ statsraw) {
    int blk = blockIdx.x;                 // 0..255
    int t = threadIdx.x;
    size_t row0 = (size_t)blk * 64;
    int qd = t & 127;
    int rh = t >> 7;
    const float* base = x + row0 * 512 + qd * 4;
    float s1 = 0.f, s2 = 0.f;
    #pragma unroll 4
    for (int i = 0; i < 32; ++i) {
        int r = rh + i * 2;
        float4 v = *reinterpret_cast<const float4*>(base + (size_t)r * 512);
        s1 += v.x + v.y + v.z + v.w;
        s2 += v.x * v.x + v.y * v.y + v.z * v.z + v.w * v.w;
    }
    __shared__ float a1[256], a2[256];
    a1[t] = s1; a2[t] = s2;
    __syncthreads();
    if (t < 32) {
        float u1 = 0.f, u2 = 0.f;
        #pragma unroll
        for (int e = 0; e < 4; ++e) {
            u1 += a1[t * 4 + e] + a1[128 + t * 4 + e];
            u2 += a2[t * 4 + e] + a2[128 + t * 4 + e];
        }
        int b = (int)(row0 >> 12);
        atomicAdd(&statsraw[(b * 32 + t) * 2],     u1);
        atomicAdd(&statsraw[(b * 32 + t) * 2 + 1], u2);
    }
}

// ---------------- GroupNorm apply ----------------
__global__ __launch_bounds__(256) void gn_apply_kernel(const float* __restrict__ x,
                                                       const float* __restrict__ statsraw,
                                                       const float* __restrict__ gsc,
                                                       const float* __restrict__ gbs,
                                                       short* __restrict__ xn) {
    int i4 = blockIdx.x * 256 + threadIdx.x;
    int base = i4 * 4;
    int b = base >> 21;
    int c = base & 511;
    int sidx = (b * 32 + (c >> 4)) * 2;
    float s1 = statsraw[sidx], s2 = statsraw[sidx + 1];
    float mean = s1 * (1.f / 65536.f);
    float var  = s2 * (1.f / 65536.f) - mean * mean;
    float rstd = rsqrtf(var + GEPS);
    float4 xv = reinterpret_cast<const float4*>(x)[i4];
    float4 sv = *reinterpret_cast<const float4*>(gsc + c);
    float4 bv = *reinterpret_cast<const float4*>(gbs + c);
    union { short s[4]; uint2 u; } p;
    p.s[0] = bf16b((xv.x - mean) * rstd * sv.x + bv.x);
    p.s[1] = bf16b((xv.y - mean) * rstd * sv.y + bv.y);
    p.s[2] = bf16b((xv.z - mean) * rstd * sv.z + bv.z);
    p.s[3] = bf16b((xv.w - mean) * rstd * sv.w + bv.w);
    reinterpret_cast<uint2*>(xn)[i4] = p.u;
}

// ---------------- weight transpose ----------------
__global__ __launch_bounds__(256) void wtrans_kernel(const float* __restrict__ w0,
                                                     const float* __restrict__ w1,
                                                     const float* __restrict__ w2,
                                                     const float* __restrict__ w3,
                                                     short* __restrict__ wT) {
    const float* w = (blockIdx.z == 0) ? w0 : (blockIdx.z == 1) ? w1
                   : (blockIdx.z == 2) ? w2 : w3;
    short* out = wT + (size_t)blockIdx.z * CH * CH;
    int n0 = blockIdx.x * 32, k0 = blockIdx.y * 32;
    int tx = threadIdx.x, ty = threadIdx.y;
    __shared__ float s[32][33];
    #pragma unroll
    for (int i = 0; i < 4; ++i) {
        int kk = ty + i * 8;
        s[kk][tx] = w[(size_t)(k0 + kk) * CH + n0 + tx];
    }
    __syncthreads();
    #pragma unroll
    for (int i = 0; i < 4; ++i) {
        int nn = ty + i * 8;
        out[(size_t)(n0 + nn) * CH + k0 + tx] = bf16b(s[tx][nn]);
    }
}

// ---------------- fused QKV GEMM: fp8 epilogue ------------------------------------
// q8/k8 row-major. vT8 column-INTERLEAVED per 32-s block: mem col 2c+u <-> s = c+16u,
// matching flash's P layout (P and V must use the same s-column order).
__global__ __launch_bounds__(256) void gemm_qkv_kernel(const short* __restrict__ A,
                                                       const short* __restrict__ wT,
                                                       const float* __restrict__ bq,
                                                       const float* __restrict__ bk,
                                                       const float* __restrict__ bv,
                                                       char* __restrict__ q8,
                                                       char* __restrict__ k8,
                                                       char* __restrict__ vT8) {
    __shared__ short As[128 * 64];
    __shared__ short Bs[128 * 64];
    __shared__ char  vls[128 * 144];   // fp8 transpose staging, pitch 144
    int m0 = blockIdx.x * 128;
    int nblk = blockIdx.y;                  // 0..11
    int which = nblk >> 2;                  // 0=q,1=k,2=v (block-uniform)
    int n0 = (nblk & 3) * 128;
    const short* BT = wT + (size_t)which * 512 * 512;
    const float* bias = (which == 0) ? bq : (which == 1) ? bk : bv;
    int t = threadIdx.x;
    int w = t >> 6, lane = t & 63;
    int wr = w >> 1, wc = w & 1;
    int l15 = lane & 15, l4 = lane >> 4;
    floatx4 acc[4][4];
    #pragma unroll
    for (int i = 0; i < 4; ++i)
        #pragma unroll
        for (int j = 0; j < 4; ++j) acc[i][j] = (floatx4){0.f, 0.f, 0.f, 0.f};

    for (int k0 = 0; k0 < 512; k0 += 64) {
        __syncthreads();
        #pragma unroll
        for (int i = 0; i < 4; ++i) {
            int c = i * 256 + t;
            int row = c >> 3, j = (c & 7) ^ (row & 7);
            dma16(&A[(size_t)(m0 + row) * 512 + k0 + j * 8], &As[(c & ~63) * 8]);
            dma16(&BT[(size_t)(n0 + row) * 512 + k0 + j * 8], &Bs[(c & ~63) * 8]);
        }
        __syncthreads();
        #pragma unroll
        for (int kk = 0; kk < 64; kk += 32) {
            short8 af[4], bf[4];
            #pragma unroll
            for (int i = 0; i < 4; ++i) {
                int row = wr * 64 + i * 16 + l15;
                int j = (kk >> 3) + l4;
                af[i] = *reinterpret_cast<const short8*>(&As[(row * 8 + (j ^ (l15 & 7))) * 8]);
            }
            #pragma unroll
            for (int j2 = 0; j2 < 4; ++j2) {
                int row = wc * 64 + j2 * 16 + l15;
                int j = (kk >> 3) + l4;
                bf[j2] = *reinterpret_cast<const short8*>(&Bs[(row * 8 + (j ^ (l15 & 7))) * 8]);
            }
            #pragma unroll
            for (int i = 0; i < 4; ++i)
                #pragma unroll
                for (int j2 = 0; j2 < 4; ++j2)
                    acc[i][j2] = __builtin_amdgcn_mfma_f32_16x16x32_bf16(af[i], bf[j2], acc[i][j2], 0, 0, 0);
        }
    }
    if (which < 2) {
        char* o8 = (which == 0) ? q8 : k8;
        #pragma unroll
        for (int i = 0; i < 4; ++i)
            #pragma unroll
            for (int j = 0; j < 4; ++j)
                #pragma unroll
                for (int r = 0; r < 4; ++r) {
                    int row = m0 + wr * 64 + i * 16 + l4 * 4 + r;
                    int col = n0 + wc * 64 + j * 16 + l15;
                    o8[(size_t)row * 512 + col] = fp8b(acc[i][j][r] + bias[col]);
                }
    } else {
        // v: transpose via LDS, with s-columns pair-interleaved per 32-block
        __syncthreads();
        #pragma unroll
        for (int i = 0; i < 4; ++i)
            #pragma unroll
            for (int j = 0; j < 4; ++j)
                #pragma unroll
                for (int r = 0; r < 4; ++r) {
                    int rl = wr * 64 + i * 16 + l4 * 4 + r;     // local row (sequence)
                    int rp = (rl & ~31) | (((rl & 15) << 1) | ((rl >> 4) & 1));  // interleave
                    int cl = wc * 64 + j * 16 + l15;            // local col (d)
                    vls[cl * 144 + rp] = fp8b(acc[i][j][r] + bias[n0 + cl]);
                }
        __syncthreads();
        int b = m0 >> 12, l0 = m0 & 4095;
        #pragma unroll
        for (int p = 0; p < 4; ++p) {
            int slot = p * 256 + t;
            int c = slot >> 3, off = (slot & 7) * 16;
            uint4 v;
            __builtin_memcpy(&v, &vls[c * 144 + off], 16);
            *reinterpret_cast<uint4*>(&vT8[((size_t)b * 512 + n0 + c) * 4096 + l0 + off]) = v;
        }
    }
}

// ---------------- output GEMM with FUSED combine: A = merge(Opart0, Opart1, ml) ------
__global__ __launch_bounds__(256) void gemm_bt_kernel(const short* __restrict__ Opart,
                                                      const float* __restrict__ ml,
                                                      const short* __restrict__ BT,
                                                      const float* __restrict__ bias,
                                                      float* __restrict__ outf,
                                                      const float* __restrict__ resid) {
    __shared__ short As[128 * 64];
    __shared__ short Bs[128 * 64];
    int m0 = blockIdx.x * 128, n0 = blockIdx.y * 128;
    int t = threadIdx.x;
    int w = t >> 6, lane = t & 63;
    int wr = w >> 1, wc = w & 1;
    int l15 = lane & 15, l4 = lane >> 4;
    const size_t PART = (size_t)BATCH * SEQ;   // 16384 rows per part
    floatx4 acc[4][4];
    #pragma unroll
    for (int i = 0; i < 4; ++i)
        #pragma unroll
        for (int j = 0; j < 4; ++j) acc[i][j] = (floatx4){0.f, 0.f, 0.f, 0.f};

    for (int k0 = 0; k0 < 512; k0 += 64) {
        __syncthreads();
        #pragma unroll
        for (int i = 0; i < 4; ++i) {
            int c = i * 256 + t;
            int rl = c >> 3, j = (c & 7) ^ (rl & 7);
            size_t rowg = (size_t)(m0 + rl);
            const short* s0 = Opart + rowg * 512 + k0 + j * 8;
            const short* s1 = s0 + PART * 512;
            uint4 a0 = *reinterpret_cast<const uint4*>(s0);
            uint4 a1 = *reinterpret_cast<const uint4*>(s1);
            float mA = ml[rowg * 2],          lA = ml[rowg * 2 + 1];
            float mB = ml[(PART + rowg) * 2], lB = ml[(PART + rowg) * 2 + 1];
            float mm = fmaxf(mA, mB);
            float e0 = __expf(mA - mm), e1 = __expf(mB - mm);
            float inv = 1.f / (e0 * lA + e1 * lB);
            e0 *= inv; e1 *= inv;
            union { uint4 u; short s[8]; } ua, ub, uo;
            ua.u = a0; ub.u = a1;
            #pragma unroll
            for (int e = 0; e < 8; ++e)
                uo.s[e] = bf16b(bf2f(ua.s[e]) * e0 + bf2f(ub.s[e]) * e1);
            *reinterpret_cast<uint4*>(&As[c * 8]) = uo.u;    // ds_write_b128
            dma16(&BT[(size_t)(n0 + rl) * 512 + k0 + j * 8], &Bs[(c & ~63) * 8]);
        }
        __syncthreads();
        #pragma unroll
        for (int kk = 0; kk < 64; kk += 32) {
            short8 af[4], bf[4];
            #pragma unroll
            for (int i = 0; i < 4; ++i) {
                int row = wr * 64 + i * 16 + l15;
                int j = (kk >> 3) + l4;
                af[i] = *reinterpret_cast<const short8*>(&As[(row * 8 + (j ^ (l15 & 7))) * 8]);
            }
            #pragma unroll
            for (int j2 = 0; j2 < 4; ++j2) {
                int row = wc * 64 + j2 * 16 + l15;
                int j = (kk >> 3) + l4;
                bf[j2] = *reinterpret_cast<const short8*>(&Bs[(row * 8 + (j ^ (l15 & 7))) * 8]);
            }
            #pragma unroll
            for (int i = 0; i < 4; ++i)
                #pragma unroll
                for (int j2 = 0; j2 < 4; ++j2)
                    acc[i][j2] = __builtin_amdgcn_mfma_f32_16x16x32_bf16(af[i], bf[j2], acc[i][j2], 0, 0, 0);
        }
    }
    #pragma unroll
    for (int i = 0; i < 4; ++i)
        #pragma unroll
        for (int j = 0; j < 4; ++j)
            #pragma unroll
            for (int r = 0; r < 4; ++r) {
                int row = m0 + wr * 64 + i * 16 + l4 * 4 + r;
                int col = n0 + wc * 64 + j * 16 + l15;
                float vv = acc[i][j][r] + bias[col];
                outf[(size_t)row * 512 + col] = vv + resid[(size_t)row * 512 + col];
            }
}

// ---------------- flash attention: fp8, pipelined dbuf, XCD-local, b16 P writes ----
__global__ __launch_bounds__(256, 2) void flash_kernel(const char* __restrict__ q8,
                                                       const char* __restrict__ k8,
                                                       const char* __restrict__ v8,
                                                       short* __restrict__ Opart,
                                                       float* __restrict__ ml) {
    __shared__ __align__(16) char smem[68096];
    int bx = blockIdx.x;                 // 0..511
    int pb = bx & 7;
    int part = pb >> 2, b = pb & 3;
    int q0 = (bx >> 3) * 64;
    int t = threadIdx.x, w = t >> 6, lane = t & 63;
    int l15 = lane & 15, l4 = lane >> 4;
    const float scale = 0.044194173824159216f;  // 1/sqrt(512)

    // Q fp8 fragments: rows w*16 + l15, all 512 k (8 B per ks-step)
    long qf[16];
    {
        const char* qrow = q8 + ((size_t)b * SEQ + q0 + w * 16 + l15) * 512;
        #pragma unroll
        for (int ks = 0; ks < 16; ++ks)
            qf[ks] = *reinterpret_cast<const long*>(qrow + ks * 32 + l4 * 8);
    }

    floatx4 acc[32];
    #pragma unroll
    for (int i = 0; i < 32; ++i) acc[i] = (floatx4){0.f, 0.f, 0.f, 0.f};
    floatx4 lacc = (floatx4){0.f, 0.f, 0.f, 0.f};
    float mused[4] = {-1e30f, -1e30f, -1e30f, -1e30f};

    const long ones = 0x3838383838383838L;   // e4m3 1.0 x8

    const char* kbase = k8 + (size_t)b * SEQ * 512;
    const char* vbase = v8 + (size_t)b * 512 * SEQ;

    const int kswz = l15 & 7;
    const int vswz = (l4 >> 1) ^ ((l15 >> 2) & 1);
    const int koff = (l4 & 1) * 8;
    const int s_begin = part * (SEQ / 2);

    // stage: K tile 32x512B, V tile 512x32B; 256 thr -> 4+4 dma16
    auto stage = [&](int s0, int buf) {
        char* Kd = smem + buf * 16384;
        char* Vd = smem + 32768 + buf * 16384;
        #pragma unroll
        for (int i = 0; i < 4; ++i) {
            int c = i * 256 + t;
            int row = c >> 5, j = (c & 31) ^ (row & 7);
            dma16(kbase + (size_t)(s0 + row) * 512 + j * 16, Kd + (size_t)(c & ~63) * 16);
        }
        #pragma unroll
        for (int i = 0; i < 4; ++i) {
            int c = i * 256 + t;
            int d = c >> 1, j = (c & 1) ^ ((d >> 2) & 1);
            dma16(vbase + (size_t)d * SEQ + s0 + j * 16, Vd + (size_t)(c & ~63) * 16);
        }
    };

    stage(s_begin, 0);
    __syncthreads();                                   // tile 0 ready

    for (int it = 0; it < 64; ++it) {
        int cur = it & 1;
        if (it + 1 < 64) stage(s_begin + (it + 1) * 32, 1 - cur);

        const char* Kb = smem + cur * 16384;
        const char* Vb = smem + 32768 + cur * 16384;

        // --- QK^T (fp8): S[16 rows][32 cols] in two 16x16 C-tiles
        floatx4 sa0 = (floatx4){0.f, 0.f, 0.f, 0.f};
        floatx4 sa1 = (floatx4){0.f, 0.f, 0.f, 0.f};
        #pragma unroll
        for (int ks = 0; ks < 16; ++ks) {
            int jc = ks * 2 + (l4 >> 1);
            int a0 = (l15 * 32 + (jc ^ kswz)) * 16 + koff;
            long b0 = *reinterpret_cast<const long*>(Kb + a0);
            long b1 = *reinterpret_cast<const long*>(Kb + a0 + 8192);
            sa0 = __builtin_amdgcn_mfma_f32_16x16x32_fp8_fp8(qf[ks], b0, sa0, 0, 0, 0);
            sa1 = __builtin_amdgcn_mfma_f32_16x16x32_fp8_fp8(qf[ks], b1, sa1, 0, 0, 0);
        }

        // --- online softmax with lazy rescale (margin 5)
        float v0[4], v1[4], nm4[4];
        bool need = false;
        #pragma unroll
        for (int r = 0; r < 4; ++r) {
            v0[r] = sa0[r] * scale; v1[r] = sa1[r] * scale;
            nm4[r] = rowmax16(fmaxf(v0[r], v1[r]));
            need |= (nm4[r] > mused[r] + 5.0f);
        }
        if (__ballot(need)) {
            #pragma unroll
            for (int r = 0; r < 4; ++r) {
                float nm = fmaxf(mused[r], nm4[r]);
                float al = __expf(mused[r] - nm);
                lacc[r] *= al;
                #pragma unroll
                for (int i = 0; i < 32; ++i) acc[i][r] *= al;
                mused[r] = nm;
            }
        }
        float p0[4], p1[4];
        #pragma unroll
        for (int r = 0; r < 4; ++r) {
            p0[r] = __expf(v0[r] - mused[r]);     // <= e^5 = 148 < 448 fp8 max
            p1[r] = __expf(v1[r] - mused[r]);
        }

        // P (fp8) write: interleaved col pairs (c, c+16) -> mem cols (2c, 2c+1).
        // 4 packed ds_write_b16, pitch 40 B -> 32 distinct banks (conflict-free).
        char* Ps = smem + 65536 + w * 640;
        #pragma unroll
        for (int r = 0; r < 4; ++r) {
            int pk = __builtin_amdgcn_cvt_pk_fp8_f32(p0[r], p1[r], 0, false);
            *reinterpret_cast<short*>(Ps + (l4 * 4 + r) * 40 + l15 * 2) = (short)pk;
        }

        // A-frag read via memcpy (may-alias pun -> ordered AFTER the short stores;
        // plain long* load is TBAA-noalias with short stores and got hoisted -> NaN in r10).
        long pf;
        __builtin_memcpy(&pf, (const char*)__builtin_assume_aligned(Ps + l15 * 40 + l4 * 8, 8), 8);
        lacc = __builtin_amdgcn_mfma_f32_16x16x32_fp8_fp8(pf, ones, lacc, 0, 0, 0);
        #pragma unroll
        for (int tt = 0; tt < 32; ++tt) {
            int d = tt * 16 + l15;
            long vf = *reinterpret_cast<const long*>(Vb + (d * 2 + vswz) * 16 + koff);
            acc[tt] = __builtin_amdgcn_mfma_f32_16x16x32_fp8_fp8(pf, vf, acc[tt], 0, 0, 0);
        }

        __syncthreads();    // drains DMA(i+1) + all reads of buf[cur] done
    }

    short* obase = Opart + (((size_t)part * BATCH + b) * SEQ + q0 + w * 16) * 512;
    #pragma unroll
    for (int r = 0; r < 4; ++r) {
        #pragma unroll
        for (int tt = 0; tt < 32; ++tt)
            obase[(size_t)(l4 * 4 + r) * 512 + tt * 16 + l15] = bf16b(acc[tt][r]);
    }
    if (l15 == 0) {
        #pragma unroll
        for (int r = 0; r < 4; ++r) {
            size_t rowg = ((size_t)part * BATCH + b) * SEQ + q0 + w * 16 + l4 * 4 + r;
            ml[rowg * 2]     = mused[r];
            ml[rowg * 2 + 1] = lacc[r];
        }
    }
}

extern "C" void kernel_launch(void* const* d_in, const int* in_sizes, int n_in,
                              void* d_out, int out_size, void* d_ws, size_t ws_size,
                              hipStream_t stream) {
    const float* x   = (const float*)d_in[0];
    const float* gsc = (const float*)d_in[1];
    const float* gbs = (const float*)d_in[2];
    const float* wq  = (const float*)d_in[3];
    const float* bq  = (const float*)d_in[4];
    const float* wk  = (const float*)d_in[5];
    const float* bk  = (const float*)d_in[6];
    const float* wv  = (const float*)d_in[7];
    const float* bv  = (const float*)d_in[8];
    const float* wo  = (const float*)d_in[9];
    const float* bo  = (const float*)d_in[10];
    float* out = (float*)d_out;

    char* ws = (char*)d_ws;
    const size_t MB = 1ull << 20;
    // [0,16)  xn bf16 (GEMM A input, dead after QKV GEMM)
    // [16,24) q8; [24,32) k8; [32,40) vT8 (fp8, from gemm_qkv epilogue)
    // [40,72) Opart bf16 (2 parts); [72,74) wT; [74,..) stats + ml
    short* xn    = (short*)ws;
    char*  q8    = (char*)(ws + 16 * MB);
    char*  k8    = (char*)(ws + 24 * MB);
    char*  vT8   = (char*)(ws + 32 * MB);
    short* Opart = (short*)(ws + 40 * MB);
    short* wT    = (short*)(ws + 72 * MB);
    float* stats = (float*)(ws + 74 * MB);
    float* ml    = (float*)(ws + 74 * MB + 65536);

    hipMemsetAsync(stats, 0, 256 * sizeof(float), stream);
    gn_partial_kernel<<<256, 256, 0, stream>>>(x, stats);
    gn_apply_kernel<<<8192, 256, 0, stream>>>(x, stats, gsc, gbs, xn);
    wtrans_kernel<<<dim3(16, 16, 4), dim3(32, 8), 0, stream>>>(wq, wk, wv, wo, wT);

    short* woT = wT + 786432;

    gemm_qkv_kernel<<<dim3(128, 12), 256, 0, stream>>>(xn, wT, bq, bk, bv, q8, k8, vT8);
    flash_kernel<<<512, 256, 0, stream>>>(q8, k8, vT8, Opart, ml);
    gemm_bt_kernel<<<dim3(128, 4), 256, 0, stream>>>(Opart, ml, woT, bo, out, x);
}